// Round 1
// baseline (923.147 us; speedup 1.0000x reference)
//
#include <hip/hip_runtime.h>
#include <hip/hip_bf16.h>

// Problem constants
#define N_TOK   576
#define MPAD    640            // padded to 5*128
#define DIM     1024
#define VOCAB   262400
#define BM      128
#define BN      128
#define BK      64
#define RB      5              // MPAD/BM row blocks
#define VBLKS   (VOCAB/BN)     // 2050
#define IGNORE_INDEX (-100)

typedef float  f32x4  __attribute__((ext_vector_type(4)));
typedef short  bf16x8 __attribute__((ext_vector_type(8)));
typedef unsigned short u16x8 __attribute__((ext_vector_type(8)));

__device__ __forceinline__ unsigned cvt_pk_bf16(float a, float b) {
  union { __hip_bfloat162 h; unsigned u; } c;
  c.h = __float22bfloat162_rn(make_float2(a, b));   // -> v_cvt_pk_bf16_f32
  return c.u;
}

// ---------- kernel 1: x fp32 -> bf16, rows [576,640) zero-padded ----------
__global__ void k_cvt_x(const float* __restrict__ x, unsigned short* __restrict__ xb) {
  int idx = blockIdx.x * 256 + threadIdx.x;     // 81920 threads * 8 elems
  long e0 = (long)idx * 8;
  int row = (int)(e0 >> 10);
  union { u16x8 v; unsigned u[4]; } o;
  if (row < N_TOK) {
    const float4 f0 = *(const float4*)(x + e0);
    const float4 f1 = *(const float4*)(x + e0 + 4);
    o.u[0] = cvt_pk_bf16(f0.x, f0.y);
    o.u[1] = cvt_pk_bf16(f0.z, f0.w);
    o.u[2] = cvt_pk_bf16(f1.x, f1.y);
    o.u[3] = cvt_pk_bf16(f1.z, f1.w);
  } else {
    o.u[0] = o.u[1] = o.u[2] = o.u[3] = 0u;
  }
  *(u16x8*)(xb + e0) = o.v;
}

// ---------- kernel 2: main GEMM + softcap + exp + row-sum ----------
// grid = RB*VBLKS, row-block fastest (5 sharers of a W tile dispatch adjacently)
__global__ __launch_bounds__(256, 2) void k_gemm(
    const float* __restrict__ W,            // [VOCAB][DIM] fp32
    const unsigned short* __restrict__ Xb,  // [MPAD][DIM] bf16
    float* __restrict__ S)                  // [MPAD] running sum of exp(z-30)
{
  __shared__ unsigned short As[BM * BK];    // [128][64] bf16
  __shared__ unsigned short Bs[BN * BK];    // [128][64] bf16

  const int bid = blockIdx.x;
  const int rb  = bid % RB;
  const int vb  = bid / RB;
  const int m0  = rb * BM;
  const long n0 = (long)vb * BN;

  const int t   = threadIdx.x;
  const int l   = t & 63;
  const int w   = t >> 6;
  const int wm  = w >> 1, wn = w & 1;       // 2x2 wave grid, 64x64 per wave
  const int l15 = l & 15, lh = l >> 4;

  f32x4 acc[4][4];
  const f32x4 zero4 = {0.0f, 0.0f, 0.0f, 0.0f};
  #pragma unroll
  for (int i = 0; i < 4; ++i)
    #pragma unroll
    for (int j = 0; j < 4; ++j) acc[i][j] = zero4;

  for (int k0 = 0; k0 < DIM; k0 += BK) {
    // ---- B global loads to regs BEFORE the barrier (latency overlap) ----
    float4 fb[4][2];
    #pragma unroll
    for (int i = 0; i < 4; ++i) {
      int lin = t + i * 256;                // oct index 0..1023
      int r   = lin >> 3;
      int ko  = (lin & 7) * 8;
      const float* g = W + (n0 + r) * DIM + k0 + ko;
      fb[i][0] = *(const float4*)g;
      fb[i][1] = *(const float4*)(g + 4);
    }
    __syncthreads();                        // prev-iter LDS reads done
    // ---- A tile: direct global->LDS, 16B per lane ----
    #pragma unroll
    for (int i = 0; i < 4; ++i) {
      int lin = t + i * 256;                // 16B-chunk index 0..1023
      int r   = lin >> 3;
      int kb  = lin & 7;
      const unsigned short* g = Xb + (size_t)(m0 + r) * DIM + k0 + kb * 8;
      __builtin_amdgcn_global_load_lds(
          (const __attribute__((address_space(1))) void*)g,
          (__attribute__((address_space(3))) void*)(As + (size_t)lin * 8),
          16, 0, 0);
    }
    // ---- B: convert + LDS write ----
    #pragma unroll
    for (int i = 0; i < 4; ++i) {
      int lin = t + i * 256;
      int r   = lin >> 3;
      int ko  = (lin & 7) * 8;
      union { u16x8 v; unsigned u[4]; } o;
      o.u[0] = cvt_pk_bf16(fb[i][0].x, fb[i][0].y);
      o.u[1] = cvt_pk_bf16(fb[i][0].z, fb[i][0].w);
      o.u[2] = cvt_pk_bf16(fb[i][1].x, fb[i][1].y);
      o.u[3] = cvt_pk_bf16(fb[i][1].z, fb[i][1].w);
      *(u16x8*)(Bs + r * BK + ko) = o.v;
    }
    __syncthreads();

    // ---- fragments + MFMA ----
    bf16x8 af[4][2], bfr[4][2];
    #pragma unroll
    for (int mi = 0; mi < 4; ++mi)
      #pragma unroll
      for (int kk = 0; kk < 2; ++kk)
        af[mi][kk] = *(const bf16x8*)(As + (wm*64 + mi*16 + l15) * BK + kk*32 + lh*8);
    #pragma unroll
    for (int ni = 0; ni < 4; ++ni)
      #pragma unroll
      for (int kk = 0; kk < 2; ++kk)
        bfr[ni][kk] = *(const bf16x8*)(Bs + (wn*64 + ni*16 + l15) * BK + kk*32 + lh*8);
    #pragma unroll
    for (int kk = 0; kk < 2; ++kk)
      #pragma unroll
      for (int mi = 0; mi < 4; ++mi)
        #pragma unroll
        for (int ni = 0; ni < 4; ++ni)
          acc[mi][ni] = __builtin_amdgcn_mfma_f32_16x16x32_bf16(
              af[mi][kk], bfr[ni][kk], acc[mi][ni], 0, 0, 0);
  }

  // ---- epilogue: p = exp(z-30) = exp(-60/(exp(g/15)+1)), row sums, atomics
  // C frag layout: col = l&15 (vocab), row = (l>>4)*4 + j (token)
  float red[4][4];
  #pragma unroll
  for (int mi = 0; mi < 4; ++mi) {
    #pragma unroll
    for (int j = 0; j < 4; ++j) {
      float s = 0.0f;
      #pragma unroll
      for (int ni = 0; ni < 4; ++ni) {
        float g   = acc[mi][ni][j];
        float tp1 = __expf(g * (1.0f / 15.0f)) + 1.0f;
        s += __expf(-60.0f * __builtin_amdgcn_rcpf(tp1));
      }
      s += __shfl_xor(s, 1);
      s += __shfl_xor(s, 2);
      s += __shfl_xor(s, 4);
      s += __shfl_xor(s, 8);
      red[mi][j] = s;                       // sum over this wave's 64 cols
    }
  }
  if (l15 == 0) {
    #pragma unroll
    for (int mi = 0; mi < 4; ++mi)
      #pragma unroll
      for (int j = 0; j < 4; ++j) {
        int row = m0 + wm*64 + mi*16 + lh*4 + j;
        atomicAdd(&S[row], red[mi][j]);     // padded rows land in S[576..640)
      }
  }
}

// ---------- kernel 3: exact fp32 target logits ----------
__global__ void k_tgt(const float* __restrict__ x, const float* __restrict__ W,
                      const int* __restrict__ labels, float* __restrict__ tgt) {
  int n = blockIdx.x;
  int lab = labels[n];
  int t = threadIdx.x;                       // 256 threads * 4 floats = 1024
  float s = 0.0f;
  if (lab >= 0) {
    const float4 a = ((const float4*)(x + (size_t)n * DIM))[t];
    const float4 b = ((const float4*)(W + (size_t)lab * DIM))[t];
    s = a.x*b.x + a.y*b.y + a.z*b.z + a.w*b.w;
  }
  #pragma unroll
  for (int off = 32; off >= 1; off >>= 1) s += __shfl_xor(s, off);
  __shared__ float wsum[4];
  if ((t & 63) == 0) wsum[t >> 6] = s;
  __syncthreads();
  if (t == 0) {
    float d = wsum[0] + wsum[1] + wsum[2] + wsum[3];
    tgt[n] = (lab >= 0) ? 30.0f * tanhf(d * (1.0f / 30.0f)) : 0.0f;
  }
}

// ---------- kernel 4: final reduce -> loss ----------
__global__ void k_final(const float* __restrict__ S, const float* __restrict__ tgt,
                        const int* __restrict__ labels, float* __restrict__ out) {
  int t = threadIdx.x;
  float sum = 0.0f, cnt = 0.0f;
  for (int n = t; n < N_TOK; n += 256) {
    if (labels[n] != IGNORE_INDEX) {
      sum += 30.0f + __logf(S[n]) - tgt[n];  // lse = 30 + log(sum exp(z-30))
      cnt += 1.0f;
    }
  }
  #pragma unroll
  for (int off = 32; off >= 1; off >>= 1) {
    sum += __shfl_xor(sum, off);
    cnt += __shfl_xor(cnt, off);
  }
  __shared__ float as_[4], ac_[4];
  if ((t & 63) == 0) { as_[t >> 6] = sum; ac_[t >> 6] = cnt; }
  __syncthreads();
  if (t == 0) {
    float ts = as_[0] + as_[1] + as_[2] + as_[3];
    float tc = ac_[0] + ac_[1] + ac_[2] + ac_[3];
    out[0] = ts / tc;
  }
}

extern "C" void kernel_launch(void* const* d_in, const int* in_sizes, int n_in,
                              void* d_out, int out_size, void* d_ws, size_t ws_size,
                              hipStream_t stream) {
  const float* x      = (const float*)d_in[0];
  const float* W      = (const float*)d_in[1];
  const int*   labels = (const int*)d_in[2];
  float* out = (float*)d_out;

  // ws layout: xb [640*1024 bf16] | S [640 f32] | tgt [576 f32]  (~1.26 MB)
  char* ws = (char*)d_ws;
  unsigned short* xb = (unsigned short*)ws;
  float* S   = (float*)(ws + (size_t)MPAD * DIM * 2);
  float* tgt = (float*)(ws + (size_t)MPAD * DIM * 2 + MPAD * 4);

  hipMemsetAsync(S, 0, MPAD * sizeof(float), stream);   // zero accumulators
  k_cvt_x<<<MPAD * DIM / (256 * 8), 256, 0, stream>>>(x, xb);
  k_gemm<<<RB * VBLKS, 256, 0, stream>>>(W, xb, S);
  k_tgt<<<N_TOK, 256, 0, stream>>>(x, W, labels, tgt);
  k_final<<<1, 256, 0, stream>>>(S, tgt, labels, out);
}

// Round 2
// 635.815 us; speedup vs baseline: 1.4519x; 1.4519x over previous
//
#include <hip/hip_runtime.h>
#include <hip/hip_bf16.h>

// Problem constants
#define N_TOK   576
#define MPAD    640            // padded to 5*128
#define DIM     1024
#define VOCAB   262400
#define BM      128
#define BN      128
#define BK      64
#define RB      5              // MPAD/BM row blocks
#define VBLKS   (VOCAB/BN)     // 2050
#define NWG     (RB*VBLKS)     // 10250
#define IGNORE_INDEX (-100)

typedef float  f32x4  __attribute__((ext_vector_type(4)));
typedef short  bf16x8 __attribute__((ext_vector_type(8)));
typedef unsigned short u16x8 __attribute__((ext_vector_type(8)));

__device__ __forceinline__ unsigned cvt_pk_bf16(float a, float b) {
  union { __hip_bfloat162 h; unsigned u; } c;
  c.h = __float22bfloat162_rn(make_float2(a, b));   // -> v_cvt_pk_bf16_f32
  return c.u;
}

// ---------- kernel 1: x fp32 -> bf16, rows [576,640) zero-padded ----------
__global__ void k_cvt_x(const float* __restrict__ x, unsigned short* __restrict__ xb) {
  int idx = blockIdx.x * 256 + threadIdx.x;     // 81920 threads * 8 elems
  long e0 = (long)idx * 8;
  int row = (int)(e0 >> 10);
  union { u16x8 v; unsigned u[4]; } o;
  if (row < N_TOK) {
    const float4 f0 = *(const float4*)(x + e0);
    const float4 f1 = *(const float4*)(x + e0 + 4);
    o.u[0] = cvt_pk_bf16(f0.x, f0.y);
    o.u[1] = cvt_pk_bf16(f0.z, f0.w);
    o.u[2] = cvt_pk_bf16(f1.x, f1.y);
    o.u[3] = cvt_pk_bf16(f1.z, f1.w);
  } else {
    o.u[0] = o.u[1] = o.u[2] = o.u[3] = 0u;
  }
  *(u16x8*)(xb + e0) = o.v;
}

// ---------- kernel 2: main GEMM + softcap + exp + row-sum ----------
// LDS layout (both tiles): 16B chunk j of row r stored at chunk (j ^ (r&7))
// within the row -> fragment reads spread across 8 bank-quads (2-way = free).
// A: global_load_lds writes linearly, so the SOURCE chunk is pre-swizzled.
// B: reg-staged, ds_write address swizzled directly.
__global__ __launch_bounds__(256, 2) void k_gemm(
    const float* __restrict__ W,            // [VOCAB][DIM] fp32
    const unsigned short* __restrict__ Xb,  // [MPAD][DIM] bf16
    float* __restrict__ S)                  // [MPAD] running sum of exp(z-30)
{
  __shared__ unsigned short As[BM * BK];    // [128][64] bf16, swizzled
  __shared__ unsigned short Bs[BN * BK];    // [128][64] bf16, swizzled

  // ---- bijective XCD swizzle (m204): contiguous logical chunk per XCD ----
  // logical order is rb-fastest, so the 5 sharers of a W tile hit one L2.
  const int q  = NWG / 8, rm = NWG % 8;     // 1281, 2
  const int orig = blockIdx.x;
  const int xcd  = orig & 7;
  const int part = orig >> 3;
  const int bid  = (xcd < rm ? xcd * (q + 1) : rm * (q + 1) + (xcd - rm) * q) + part;

  const int rb  = bid % RB;
  const int vb  = bid / RB;
  const int m0  = rb * BM;
  const long n0 = (long)vb * BN;

  const int t   = threadIdx.x;
  const int l   = t & 63;
  const int w   = t >> 6;
  const int wm  = w >> 1, wn = w & 1;       // 2x2 wave grid, 64x64 per wave
  const int l15 = l & 15, lh = l >> 4;
  const int e8  = l15 & 7;                  // row&7 for fragment rows

  f32x4 acc[4][4];
  const f32x4 zero4 = {0.0f, 0.0f, 0.0f, 0.0f};
  #pragma unroll
  for (int i = 0; i < 4; ++i)
    #pragma unroll
    for (int j = 0; j < 4; ++j) acc[i][j] = zero4;

  for (int k0 = 0; k0 < DIM; k0 += BK) {
    // ---- B global loads to regs BEFORE the barrier (latency overlap) ----
    float4 fb[4][2];
    #pragma unroll
    for (int i = 0; i < 4; ++i) {
      int lin = t + i * 256;                // oct index 0..1023
      int r   = lin >> 3;
      int ko  = (lin & 7) * 8;
      const float* g = W + (n0 + r) * DIM + k0 + ko;
      fb[i][0] = *(const float4*)g;
      fb[i][1] = *(const float4*)(g + 4);
    }
    __syncthreads();                        // prev-iter LDS reads done
    // ---- A tile: direct global->LDS, linear dest, pre-swizzled source ----
    #pragma unroll
    for (int i = 0; i < 4; ++i) {
      int lin = t + i * 256;                // 16B-chunk index 0..1023
      int r   = lin >> 3;
      int kb  = (lin & 7) ^ (r & 7);        // inverse swizzle on source
      const unsigned short* g = Xb + (size_t)(m0 + r) * DIM + k0 + kb * 8;
      __builtin_amdgcn_global_load_lds(
          (const __attribute__((address_space(1))) void*)g,
          (__attribute__((address_space(3))) void*)(As + (size_t)lin * 8),
          16, 0, 0);
    }
    // ---- B: convert + swizzled LDS write ----
    #pragma unroll
    for (int i = 0; i < 4; ++i) {
      int lin = t + i * 256;
      int r   = lin >> 3;
      int c   = (lin & 7) ^ (r & 7);        // swizzled chunk slot
      union { u16x8 v; unsigned u[4]; } o;
      o.u[0] = cvt_pk_bf16(fb[i][0].x, fb[i][0].y);
      o.u[1] = cvt_pk_bf16(fb[i][0].z, fb[i][0].w);
      o.u[2] = cvt_pk_bf16(fb[i][1].x, fb[i][1].y);
      o.u[3] = cvt_pk_bf16(fb[i][1].z, fb[i][1].w);
      *(u16x8*)(Bs + r * BK + c * 8) = o.v;
    }
    __syncthreads();

    // ---- fragments (swizzled read) + MFMA ----
    bf16x8 af[4][2], bfr[4][2];
    #pragma unroll
    for (int mi = 0; mi < 4; ++mi)
      #pragma unroll
      for (int kk = 0; kk < 2; ++kk)
        af[mi][kk] = *(const bf16x8*)(As + (wm*64 + mi*16 + l15) * BK
                                         + (((kk*4 + lh) ^ e8) * 8));
    #pragma unroll
    for (int ni = 0; ni < 4; ++ni)
      #pragma unroll
      for (int kk = 0; kk < 2; ++kk)
        bfr[ni][kk] = *(const bf16x8*)(Bs + (wn*64 + ni*16 + l15) * BK
                                          + (((kk*4 + lh) ^ e8) * 8));
    #pragma unroll
    for (int kk = 0; kk < 2; ++kk)
      #pragma unroll
      for (int mi = 0; mi < 4; ++mi)
        #pragma unroll
        for (int ni = 0; ni < 4; ++ni)
          acc[mi][ni] = __builtin_amdgcn_mfma_f32_16x16x32_bf16(
              af[mi][kk], bfr[ni][kk], acc[mi][ni], 0, 0, 0);
  }

  // ---- epilogue: p = exp(z-30) = exp(-60/(exp(g/15)+1)), row sums, atomics
  // C frag layout: col = l&15 (vocab), row = (l>>4)*4 + j (token)
  float red[4][4];
  #pragma unroll
  for (int mi = 0; mi < 4; ++mi) {
    #pragma unroll
    for (int j = 0; j < 4; ++j) {
      float s = 0.0f;
      #pragma unroll
      for (int ni = 0; ni < 4; ++ni) {
        float g   = acc[mi][ni][j];
        float tp1 = __expf(g * (1.0f / 15.0f)) + 1.0f;
        s += __expf(-60.0f * __builtin_amdgcn_rcpf(tp1));
      }
      s += __shfl_xor(s, 1);
      s += __shfl_xor(s, 2);
      s += __shfl_xor(s, 4);
      s += __shfl_xor(s, 8);
      red[mi][j] = s;                       // sum over this wave's 64 cols
    }
  }
  if (l15 == 0) {
    #pragma unroll
    for (int mi = 0; mi < 4; ++mi)
      #pragma unroll
      for (int j = 0; j < 4; ++j) {
        int row = m0 + wm*64 + mi*16 + lh*4 + j;
        atomicAdd(&S[row], red[mi][j]);     // padded rows land in S[576..640)
      }
  }
}

// ---------- kernel 3: exact fp32 target logits ----------
__global__ void k_tgt(const float* __restrict__ x, const float* __restrict__ W,
                      const int* __restrict__ labels, float* __restrict__ tgt) {
  int n = blockIdx.x;
  int lab = labels[n];
  int t = threadIdx.x;                       // 256 threads * 4 floats = 1024
  float s = 0.0f;
  if (lab >= 0) {
    const float4 a = ((const float4*)(x + (size_t)n * DIM))[t];
    const float4 b = ((const float4*)(W + (size_t)lab * DIM))[t];
    s = a.x*b.x + a.y*b.y + a.z*b.z + a.w*b.w;
  }
  #pragma unroll
  for (int off = 32; off >= 1; off >>= 1) s += __shfl_xor(s, off);
  __shared__ float wsum[4];
  if ((t & 63) == 0) wsum[t >> 6] = s;
  __syncthreads();
  if (t == 0) {
    float d = wsum[0] + wsum[1] + wsum[2] + wsum[3];
    tgt[n] = (lab >= 0) ? 30.0f * tanhf(d * (1.0f / 30.0f)) : 0.0f;
  }
}

// ---------- kernel 4: final reduce -> loss ----------
__global__ void k_final(const float* __restrict__ S, const float* __restrict__ tgt,
                        const int* __restrict__ labels, float* __restrict__ out) {
  int t = threadIdx.x;
  float sum = 0.0f, cnt = 0.0f;
  for (int n = t; n < N_TOK; n += 256) {
    if (labels[n] != IGNORE_INDEX) {
      sum += 30.0f + __logf(S[n]) - tgt[n];  // lse = 30 + log(sum exp(z-30))
      cnt += 1.0f;
    }
  }
  #pragma unroll
  for (int off = 32; off >= 1; off >>= 1) {
    sum += __shfl_xor(sum, off);
    cnt += __shfl_xor(cnt, off);
  }
  __shared__ float as_[4], ac_[4];
  if ((t & 63) == 0) { as_[t >> 6] = sum; ac_[t >> 6] = cnt; }
  __syncthreads();
  if (t == 0) {
    float ts = as_[0] + as_[1] + as_[2] + as_[3];
    float tc = ac_[0] + ac_[1] + ac_[2] + ac_[3];
    out[0] = ts / tc;
  }
}

extern "C" void kernel_launch(void* const* d_in, const int* in_sizes, int n_in,
                              void* d_out, int out_size, void* d_ws, size_t ws_size,
                              hipStream_t stream) {
  const float* x      = (const float*)d_in[0];
  const float* W      = (const float*)d_in[1];
  const int*   labels = (const int*)d_in[2];
  float* out = (float*)d_out;

  // ws layout: xb [640*1024 bf16] | S [640 f32] | tgt [576 f32]  (~1.26 MB)
  char* ws = (char*)d_ws;
  unsigned short* xb = (unsigned short*)ws;
  float* S   = (float*)(ws + (size_t)MPAD * DIM * 2);
  float* tgt = (float*)(ws + (size_t)MPAD * DIM * 2 + MPAD * 4);

  hipMemsetAsync(S, 0, MPAD * sizeof(float), stream);   // zero accumulators
  k_cvt_x<<<MPAD * DIM / (256 * 8), 256, 0, stream>>>(x, xb);
  k_gemm<<<NWG, 256, 0, stream>>>(W, xb, S);
  k_tgt<<<N_TOK, 256, 0, stream>>>(x, W, labels, tgt);
  k_final<<<1, 256, 0, stream>>>(S, tgt, labels, out);
}